// Round 4
// baseline (1229.057 us; speedup 1.0000x reference)
//
#include <hip/hip_runtime.h>
#include <stdint.h>

typedef unsigned short u16;
typedef __attribute__((ext_vector_type(8))) short sx8;   // 8 bf16 (4 VGPRs) — MFMA A/B frag
typedef __attribute__((ext_vector_type(4))) float fx4;   // MFMA C/D frag

__device__ __forceinline__ float bf2f(u16 u) {
    union { unsigned i; float f; } v; v.i = ((unsigned)u) << 16; return v.f;
}
__device__ __forceinline__ u16 f2bf(float f) {
    union { float f; unsigned i; } v; v.f = f;
    return (u16)((v.i + 0x7FFFu + ((v.i >> 16) & 1u)) >> 16);
}
#define MFMA(a, b, c) __builtin_amdgcn_mfma_f32_16x16x32_bf16((a), (b), (c), 0, 0, 0)

#define GLDS(gp, lp) \
    __builtin_amdgcn_global_load_lds((const __attribute__((address_space(1))) void*)(gp), \
                                     (__attribute__((address_space(3))) void*)(lp), 16, 0, 0)

// ---------- m97-style MFMA GEMM: C[M,N] = A[M,K] @ BT[N,K]^T, all bf16 ----------
// scaleZ0: when set, `scale` applies only to batch z==0 (used to fold the 1/8
// attention scale into the Q projection of the fused QKV GEMM).
template<int BN>
__global__ __launch_bounds__(256) void gemm_bt(
    const u16* __restrict__ A, long sA, int ldA,
    const u16* __restrict__ BT, long sBT, int ldBT,
    u16* __restrict__ C, long sC, int ldC,
    int K,
    const u16* __restrict__ bias, int bz,
    const void* __restrict__ resid, int residF32, long rofs,
    float scale, int scaleZ0, int relu)
{
    constexpr int BK = 32;
    constexpr int TM = 4;
    constexpr int TN = BN / 32;
    constexpr int AI = 2;
    constexpr int BI = BN / 64;

    __shared__ __align__(16) u16 As[128 * BK];
    __shared__ __align__(16) u16 Bs[BN * BK];

    const int tid  = threadIdx.x;
    const int w    = tid >> 6;
    const int lane = tid & 63;
    const int quad = lane >> 4;
    const int n16  = lane & 15;
    const int wrow = w >> 1, wcol = w & 1;

    // XCD-chunked swizzle over the (x,y) plane (bijective when nxy%8==0)
    int bx = blockIdx.x, by = blockIdx.y;
    {
        int nxy = gridDim.x * gridDim.y;
        if ((nxy & 7) == 0) {
            int bid = by * gridDim.x + bx;
            int wgs = (bid & 7) * (nxy >> 3) + (bid >> 3);
            bx = wgs % gridDim.x;
            by = wgs / gridDim.x;
        }
    }
    const int m0 = by * 128, n0 = bx * BN;
    const long z = blockIdx.z;
    const float es = (z == 0 || !scaleZ0) ? scale : 1.f;
    A  += z * sA;
    BT += z * sBT;
    C  += z * sC;

    fx4 acc[TM][TN] = {};

    for (int k0 = 0; k0 < K; k0 += BK) {
        #pragma unroll
        for (int i = 0; i < AI; ++i) {
            unsigned base = (unsigned)(w * AI + i) * 1024u;
            unsigned off  = base + (unsigned)lane * 16u;
            unsigned row  = off >> 6;
            unsigned col  = (off & 63u) >> 1;
            GLDS(A + (long)(m0 + row) * ldA + k0 + col, (char*)As + base);
        }
        #pragma unroll
        for (int i = 0; i < BI; ++i) {
            unsigned base = (unsigned)(w * BI + i) * 1024u;
            unsigned off  = base + (unsigned)lane * 16u;
            unsigned row  = off >> 6;
            unsigned col  = (off & 63u) >> 1;
            GLDS(BT + (long)(n0 + row) * ldBT + k0 + col, (char*)Bs + base);
        }
        __syncthreads();

        sx8 af[TM], bfr[TN];
        #pragma unroll
        for (int r = 0; r < TM; ++r)
            af[r] = *(const sx8*)&As[(wrow * 64 + r * 16 + n16) * BK + quad * 8];
        #pragma unroll
        for (int c = 0; c < TN; ++c)
            bfr[c] = *(const sx8*)&Bs[(wcol * (TN * 16) + c * 16 + n16) * BK + quad * 8];
        #pragma unroll
        for (int r = 0; r < TM; ++r)
            #pragma unroll
            for (int c = 0; c < TN; ++c)
                acc[r][c] = MFMA(af[r], bfr[c], acc[r][c]);
        __syncthreads();
    }

    #pragma unroll
    for (int r = 0; r < TM; ++r) {
        int row = m0 + wrow * 64 + r * 16 + quad * 4;
        #pragma unroll
        for (int c = 0; c < TN; ++c) {
            int col = n0 + wcol * (TN * 16) + c * 16 + n16;
            float bv = bias ? bf2f(bias[bz * (int)z + col]) : 0.f;
            #pragma unroll
            for (int g = 0; g < 4; ++g) {
                long idx = (long)(row + g) * ldC + col;
                float xv = acc[r][c][g] * es + bv;
                if (resid)
                    xv += residF32 ? ((const float*)resid)[rofs + idx]
                                   : bf2f(((const u16*)resid)[rofs + idx]);
                if (relu) xv = fmaxf(xv, 0.f);
                C[idx] = f2bf(xv);
            }
        }
    }
}

// ---------- fused attention, barrier-free softmax-in-register design ----------
// Head-softmax is over h at fixed (l,m). With swapped QK (mfma(K,Q)), the MFMA
// C/D lane map (col=l=n16, row=m=quad*4+reg) is HEAD-INVARIANT, so one wave
// computing all 16 heads of a 16l x 16m S-tile holds, per lane, all 16 head
// values of its 4 (l,m) positions -> softmax is pure per-lane register math.
// No S round-trip through LDS, no __syncthreads in the main loop.
//   - block = 4 waves; wave w owns d-tile dt=w for PV (QK redundant x4, cheap)
//   - Q[16h][16l][64d] staged once in XOR-swizzled LDS (one __syncthreads)
//   - P^T -> A-frag transpose via 2KB wave-PRIVATE LDS scratch (b64 writes /
//     b128 reads, within-wave ordering only)
//   - one raw s_barrier per iter keeps the 4 waves' identical K streams
//     L1-aligned (K frags read from global; L1 shares across waves)
//   - XCD-chunked swizzle: 64 consecutive blocks = one batch b per XCD ->
//     K+V working set = 4MB = its L2 (R3-proven fetch reduction)
//   - NOTE: Q is pre-scaled by 1/8 in the QKV GEMM; S here is used raw.
// qb [b][16h][1024 l][64 d]; kt [(b,h)][m][d] reshape-view K_t; vt [b][16h][64 d][1024 m].
__global__ __launch_bounds__(256, 2) void attn_reg(
    const u16* __restrict__ qb, const u16* __restrict__ kt,
    const u16* __restrict__ vt, const int* __restrict__ mask,
    u16* __restrict__ ao)
{
    __shared__ __align__(16) char Lds[32768 + 4 * 2048];  // Qs 32KB + 2KB scratch/wave

    const int tid = threadIdx.x, w = tid >> 6, lane = tid & 63;
    const int quad = lane >> 4, n16 = lane & 15;

    // XCD-chunked swizzle: 512 blocks, 8 XCDs -> 64 consecutive wg per XCD = one b
    const int wg = ((blockIdx.x & 7) << 6) + (blockIdx.x >> 3);
    const int l0 = (wg & 63) * 16;
    const long bo = (long)(wg >> 6) * 1048576;
    const int dt = w;

    // ---- stage Q[16h][16l][64d] into XOR-swizzled LDS (layout [h][l][d]) ----
    {
        const int r8 = lane >> 3, c8 = lane & 7;
        #pragma unroll
        for (int i = 0; i < 4; ++i) {
            const int h = w * 4 + i;
            #pragma unroll
            for (int j = 0; j < 2; ++j) {
                const int row = r8 + j * 8;
                const u16* src = qb + bo + h * 65536 + (long)(l0 + row) * 64 + c8 * 8;
                const int dst = h * 2048 + row * 128 + ((c8 * 16) ^ ((row & 7) << 4));
                *(uint4*)(Lds + dst) = *(const uint4*)src;
            }
        }
    }
    __syncthreads();

    char* scr = Lds + 32768 + w * 2048;
    const int qo0 = n16 * 128 + ((quad * 16) ^ ((n16 & 7) << 4));
    const int qo1 = n16 * 128 + ((64 + quad * 16) ^ ((n16 & 7) << 4));
    const int pw0 = n16 * 64 + ((quad * 8) ^ ((n16 & 3) << 4));
    const int pw1 = n16 * 64 + ((32 + quad * 8) ^ ((n16 & 3) << 4));
    const int prd = n16 * 64 + ((quad * 16) ^ ((n16 & 3) << 4));

    fx4 of[16] = {};   // O accumulators, one 16l x 16d tile per head

    for (int itp = 0; itp < 32; ++itp) {
        const int m0 = itp * 32;
        __builtin_amdgcn_s_barrier();   // timing-only: keep K streams L1-aligned
        uint2 pc0[16], pc1[16];
        #pragma unroll
        for (int sub = 0; sub < 2; ++sub) {
            const int ms = m0 + sub * 16;
            fx4 s[16];
            const u16* kb = kt + bo + (long)(ms + n16) * 64 + quad * 8;
            #pragma unroll
            for (int h = 0; h < 16; ++h) {
                const u16* kp = kb + h * 65536;
                sx8 k0 = *(const sx8*)kp;
                sx8 k1 = *(const sx8*)(kp + 32);
                sx8 q0 = *(const sx8*)(Lds + h * 2048 + qo0);
                sx8 q1 = *(const sx8*)(Lds + h * 2048 + qo1);
                fx4 acc = {};
                acc = MFMA(k0, q0, acc);
                acc = MFMA(k1, q1, acc);
                s[h] = acc;   // S^T(m = ms+quad*4+r, l = l0+n16), head h
            }
            // ---- mask + softmax over the 16 heads, per-lane registers ----
            const int4 mk = *(const int4*)&mask[bo + (long)(l0 + n16) * 1024 + ms + quad * 4];
            const int mkk[4] = {mk.x, mk.y, mk.z, mk.w};
            #pragma unroll
            for (int r = 0; r < 4; ++r) {
                float mx = -1e30f;
                #pragma unroll
                for (int h = 0; h < 16; ++h) {
                    float t = mkk[r] ? s[h][r] : -1e-12f;
                    s[h][r] = t;
                    mx = fmaxf(mx, t);
                }
                float sum = 0.f;
                #pragma unroll
                for (int h = 0; h < 16; ++h) {
                    float e = __expf(s[h][r] - mx);
                    s[h][r] = e;
                    sum += e;
                }
                const float inv = 1.f / sum;
                #pragma unroll
                for (int h = 0; h < 16; ++h) s[h][r] *= inv;
            }
            // ---- pack P to bf16 m-pairs ----
            uint2* pc = sub ? pc1 : pc0;
            #pragma unroll
            for (int h = 0; h < 16; ++h) {
                unsigned a0, a1;
                asm("v_cvt_pk_bf16_f32 %0, %1, %2" : "=v"(a0) : "v"(s[h][0]), "v"(s[h][1]));
                asm("v_cvt_pk_bf16_f32 %0, %1, %2" : "=v"(a1) : "v"(s[h][2]), "v"(s[h][3]));
                pc[h].x = a0; pc[h].y = a1;
            }
        }
        // ---- PV: of[h] += P_h @ V_h over this 32-m chunk ----
        // P^T->A-frag transpose through 2-slot wave-private scratch (depth-2 pipe)
        const u16* vb_ = vt + bo + (long)(dt * 16 + n16) * 1024 + m0 + quad * 8;
        #pragma unroll
        for (int h = 0; h < 16; ++h) {
            char* slot = scr + (h & 1) * 1024;
            *(uint2*)(slot + pw0) = pc0[h];
            *(uint2*)(slot + pw1) = pc1[h];
            sx8 pa = *(const sx8*)(slot + prd);
            sx8 vf = *(const sx8*)(vb_ + h * 65536);
            of[h] = MFMA(pa, vf, of[h]);
        }
    }

    // ---- epilogue: head-major flat store ----
    #pragma unroll
    for (int h = 0; h < 16; ++h)
        #pragma unroll
        for (int r = 0; r < 4; ++r)
            ao[bo + h * 65536 + (long)(l0 + quad * 4 + r) * 64 + dt * 16 + n16]
                = f2bf(of[h][r]);
}

// ---------- fp32 -> bf16 elementwise ----------
__global__ __launch_bounds__(256) void convert_f2b(
    const float* __restrict__ in, u16* __restrict__ out)
{
    long i = ((long)blockIdx.x * 256 + threadIdx.x) * 4;
    fx4 v = *(const fx4*)(in + i);
    uint2 o;
    o.x = (unsigned)f2bf(v[0]) | ((unsigned)f2bf(v[1]) << 16);
    o.y = (unsigned)f2bf(v[2]) | ((unsigned)f2bf(v[3]) << 16);
    *(uint2*)(out + i) = o;
}

// ---------- fp32 [R][C] -> bf16 transposed [C][R] ----------
__global__ __launch_bounds__(256) void transpose_f2b(
    const float* __restrict__ in, u16* __restrict__ out, int R, int C)
{
    __shared__ float t[32][33];
    int c0 = blockIdx.x * 32, r0 = blockIdx.y * 32;
    int tx = threadIdx.x & 31, ty = threadIdx.x >> 5;
    #pragma unroll
    for (int i = 0; i < 4; ++i)
        t[ty + i * 8][tx] = in[(long)(r0 + ty + i * 8) * C + c0 + tx];
    __syncthreads();
    #pragma unroll
    for (int i = 0; i < 4; ++i)
        out[(long)(c0 + ty + i * 8) * R + r0 + tx] = f2bf(t[tx][ty + i * 8]);
}

// ---------- bf16 batched transpose ----------
__global__ __launch_bounds__(256) void transpose_bf(
    const u16* __restrict__ in, u16* __restrict__ out, int R, int C)
{
    __shared__ u16 t[32][33];
    long zoff = (long)blockIdx.z * (long)R * (long)C;
    in += zoff; out += zoff;
    int c0 = blockIdx.x * 32, r0 = blockIdx.y * 32;
    int tx = threadIdx.x & 31, ty = threadIdx.x >> 5;
    #pragma unroll
    for (int i = 0; i < 4; ++i)
        t[ty + i * 8][tx] = in[(long)(r0 + ty + i * 8) * C + c0 + tx];
    __syncthreads();
    #pragma unroll
    for (int i = 0; i < 4; ++i)
        out[(long)(c0 + ty + i * 8) * R + r0 + tx] = t[tx][ty + i * 8];
}

// ---------- pack biases fp32 -> bf16 [bq|bk|bv|bc|b1|b2]; bq pre-scaled 1/8 ----------
__global__ __launch_bounds__(256) void pack_bias(
    const float* bq, const float* bk, const float* bv, const float* bc,
    const float* b1, const float* b2, u16* __restrict__ out)
{
    int i = blockIdx.x * 256 + threadIdx.x;
    float v;
    if      (i < 1024) v = bq[i] * 0.125f;
    else if (i < 2048) v = bk[i - 1024];
    else if (i < 3072) v = bv[i - 2048];
    else if (i < 4096) v = bc[i - 3072];
    else if (i < 8192) v = b1[i - 4096];
    else               v = b2[i - 8192];
    out[i] = f2bf(v);
}

// ---------- LayerNorm (ddof=1, /(std+eps)) ----------
__global__ __launch_bounds__(256) void layernorm_row(
    const u16* __restrict__ in, const float* __restrict__ g,
    const float* __restrict__ be, void* __restrict__ out, int outF32)
{
    int wave = threadIdx.x >> 6, lane = threadIdx.x & 63;
    long row = (long)blockIdx.x * 4 + wave;
    const u16* p = in + row * 1024 + lane * 16;

    float x[16];
    uint4 a = ((const uint4*)p)[0], b = ((const uint4*)p)[1];
    {
        unsigned u;
        u = a.x; x[0] = bf2f(u & 0xffff);  x[1] = bf2f(u >> 16);
        u = a.y; x[2] = bf2f(u & 0xffff);  x[3] = bf2f(u >> 16);
        u = a.z; x[4] = bf2f(u & 0xffff);  x[5] = bf2f(u >> 16);
        u = a.w; x[6] = bf2f(u & 0xffff);  x[7] = bf2f(u >> 16);
        u = b.x; x[8] = bf2f(u & 0xffff);  x[9] = bf2f(u >> 16);
        u = b.y; x[10] = bf2f(u & 0xffff); x[11] = bf2f(u >> 16);
        u = b.z; x[12] = bf2f(u & 0xffff); x[13] = bf2f(u >> 16);
        u = b.w; x[14] = bf2f(u & 0xffff); x[15] = bf2f(u >> 16);
    }
    float s = 0.f, ss = 0.f;
    #pragma unroll
    for (int i = 0; i < 16; ++i) { s += x[i]; ss += x[i] * x[i]; }
    #pragma unroll
    for (int o = 32; o >= 1; o >>= 1) { s += __shfl_down(s, o); ss += __shfl_down(ss, o); }
    s = __shfl(s, 0); ss = __shfl(ss, 0);
    float mean = s * (1.f / 1024.f);
    float var  = fmaxf((ss - 1024.f * mean * mean) * (1.f / 1023.f), 0.f);
    float rinv = 1.f / (sqrtf(var) + 1e-12f);

    int col = lane * 16;
    if (outF32) {
        float* ov = (float*)out + row * 1024 + col;
        #pragma unroll
        for (int i = 0; i < 16; ++i)
            ov[i] = g[col + i] * ((x[i] - mean) * rinv) + be[col + i];
    } else {
        u16* ov = (u16*)out + row * 1024 + col;
        #pragma unroll
        for (int i = 0; i < 16; ++i)
            ov[i] = f2bf(g[col + i] * ((x[i] - mean) * rinv) + be[col + i]);
    }
}

// ---------- launch ----------
// ws map (MB; peak 96 + 18KB bias):
//  [0,16)  xb -> ao (attn out, overlays dead xb)
//  [16,22) wqkvT  [22,24) wcT
//  [24,40) qb -> t0/x1
//  [40,56) kb -> vt (full V^T over dead kb) -> fh lower
//  [56,72) vb -> fh upper
//  [72,88) kt (reshape-view K_t, all b) -> w1T/w2T post-attention
//  [88,96) pre2 (FFN phase)
//  [96,+18KB) packed biases
extern "C" void kernel_launch(void* const* d_in, const int* in_sizes, int n_in,
                              void* d_out, int out_size, void* d_ws, size_t ws_size,
                              hipStream_t stream)
{
    const float* xf  = (const float*)d_in[0];
    const int* mask  = (const int*)d_in[1];
    const float* wq = (const float*)d_in[2];  const float* bq = (const float*)d_in[3];
    const float* wk = (const float*)d_in[4];  const float* bk = (const float*)d_in[5];
    const float* wv = (const float*)d_in[6];  const float* bv = (const float*)d_in[7];
    const float* wc = (const float*)d_in[8];  const float* bc = (const float*)d_in[9];
    const float* g1 = (const float*)d_in[10]; const float* be1 = (const float*)d_in[11];
    const float* w1 = (const float*)d_in[12]; const float* b1 = (const float*)d_in[13];
    const float* w2 = (const float*)d_in[14]; const float* b2 = (const float*)d_in[15];
    const float* g2 = (const float*)d_in[16]; const float* be2 = (const float*)d_in[17];

    char* ws = (char*)d_ws;
    const long MB = 1 << 20;
    u16* xb    = (u16*)(ws + 0 * MB);
    u16* wqkvT = (u16*)(ws + 16 * MB);
    u16* wcT   = (u16*)(ws + 22 * MB);
    u16* qb    = (u16*)(ws + 24 * MB);
    u16* kb    = (u16*)(ws + 40 * MB);
    u16* vb    = (u16*)(ws + 56 * MB);
    u16* kt    = (u16*)(ws + 72 * MB);
    u16* vt    = (u16*)(ws + 40 * MB);     // full V^T overlays dead kb
    u16* biasp = (u16*)(ws + 96 * MB);
    u16* ao   = xb;                        // attn out overlays dead xb
    u16* t0   = qb;
    u16* fh   = kb;
    u16* w1T  = (u16*)(ws + 72 * MB);      // overlay kt post-attention
    u16* w2T  = (u16*)(ws + 80 * MB);
    u16* pre2 = (u16*)(ws + 88 * MB);

    dim3 blk(256);
    const long M1 = 1048576;

    // phase 0: conversions
    convert_f2b<<<dim3(8192), blk, 0, stream>>>(xf, xb);
    transpose_f2b<<<dim3(32, 32), blk, 0, stream>>>(wq, wqkvT, 1024, 1024);
    transpose_f2b<<<dim3(32, 32), blk, 0, stream>>>(wk, wqkvT + M1, 1024, 1024);
    transpose_f2b<<<dim3(32, 32), blk, 0, stream>>>(wv, wqkvT + 2 * M1, 1024, 1024);
    transpose_f2b<<<dim3(32, 32), blk, 0, stream>>>(wc, wcT, 1024, 1024);
    pack_bias<<<dim3(36), blk, 0, stream>>>(bq, bk, bv, bc, b1, b2, biasp);

    // phase 1: fused QKV (Q projection pre-scaled by 1/8: scale=0.125, z==0 only)
    gemm_bt<128><<<dim3(8, 64, 3), blk, 0, stream>>>(
        xb, 0, 1024, wqkvT, M1, 1024, qb, 8 * M1, 1024, 1024,
        biasp, 1024, nullptr, 0, 0, 0.125f, 1, 0);

    // phase 2: kt = reshape-view K_t transposed to [m][d], all (b,h)
    //          (must precede vt, which overwrites kb)
    transpose_bf<<<dim3(32, 2, 128), blk, 0, stream>>>(kb, kt, 64, 1024);

    // phase 3: full V^T, then barrier-free fused attention (512 blocks, 2/CU)
    transpose_bf<<<dim3(2, 32, 128), blk, 0, stream>>>(vb, vt, 1024, 64);
    attn_reg<<<dim3(512), blk, 0, stream>>>(qb, kt, vt, mask, ao);

    // phase 4: out-proj + bias + resid(x) -> t0 ; LN1 in-place
    gemm_bt<128><<<dim3(8, 64, 1), blk, 0, stream>>>(
        ao, 0, 1024, wcT, 0, 1024, t0, 0, 1024, 1024,
        biasp + 3072, 0, xf, 1, 0, 1.f, 0, 0);
    layernorm_row<<<dim3(2048), blk, 0, stream>>>(t0, g1, be1, t0, 0);

    // phase 5: FFN weight transposes into dead kt region
    transpose_f2b<<<dim3(128, 32), blk, 0, stream>>>(w1, w1T, 1024, 4096);
    transpose_f2b<<<dim3(32, 128), blk, 0, stream>>>(w2, w2T, 4096, 1024);

    // phase 6: FFN + LN2, 2 chunks of 4096 rows
    for (int c = 0; c < 2; ++c) {
        long r0 = (long)c * 4096 * 1024;
        gemm_bt<128><<<dim3(32, 32, 1), blk, 0, stream>>>(
            t0 + r0, 0, 1024, w1T, 0, 1024, fh, 0, 4096, 1024,
            biasp + 4096, 0, nullptr, 0, 0, 1.f, 0, 1);
        gemm_bt<64><<<dim3(16, 32, 1), blk, 0, stream>>>(
            fh, 0, 4096, w2T, 0, 4096, pre2, 0, 1024, 4096,
            biasp + 8192, 0, t0 + r0, 0, 0, 1.f, 0, 0);
        layernorm_row<<<dim3(1024), blk, 0, stream>>>(
            pre2, g2, be2, (float*)d_out + r0, 1);
    }
}

// Round 5
// 934.272 us; speedup vs baseline: 1.3155x; 1.3155x over previous
//
#include <hip/hip_runtime.h>
#include <stdint.h>

typedef unsigned short u16;
typedef __attribute__((ext_vector_type(8))) short sx8;   // 8 bf16 (4 VGPRs) — MFMA A/B frag
typedef __attribute__((ext_vector_type(4))) float fx4;   // MFMA C/D frag

__device__ __forceinline__ float bf2f(u16 u) {
    union { unsigned i; float f; } v; v.i = ((unsigned)u) << 16; return v.f;
}
__device__ __forceinline__ u16 f2bf(float f) {
    union { float f; unsigned i; } v; v.f = f;
    return (u16)((v.i + 0x7FFFu + ((v.i >> 16) & 1u)) >> 16);
}
#define MFMA(a, b, c) __builtin_amdgcn_mfma_f32_16x16x32_bf16((a), (b), (c), 0, 0, 0)

#define GLDS(gp, lp) \
    __builtin_amdgcn_global_load_lds((const __attribute__((address_space(1))) void*)(gp), \
                                     (__attribute__((address_space(3))) void*)(lp), 16, 0, 0)

// ---------- m97-style MFMA GEMM: C[M,N] = A[M,K] @ BT[N,K]^T, all bf16 ----------
// scaleZ0: when set, `scale` applies only to batch z==0 (folds the 1/8
// attention scale into the Q projection of the fused QKV GEMM).
template<int BN>
__global__ __launch_bounds__(256) void gemm_bt(
    const u16* __restrict__ A, long sA, int ldA,
    const u16* __restrict__ BT, long sBT, int ldBT,
    u16* __restrict__ C, long sC, int ldC,
    int K,
    const u16* __restrict__ bias, int bz,
    const void* __restrict__ resid, int residF32, long rofs,
    float scale, int scaleZ0, int relu)
{
    constexpr int BK = 32;
    constexpr int TM = 4;
    constexpr int TN = BN / 32;
    constexpr int AI = 2;
    constexpr int BI = BN / 64;

    __shared__ __align__(16) u16 As[128 * BK];
    __shared__ __align__(16) u16 Bs[BN * BK];

    const int tid  = threadIdx.x;
    const int w    = tid >> 6;
    const int lane = tid & 63;
    const int quad = lane >> 4;
    const int n16  = lane & 15;
    const int wrow = w >> 1, wcol = w & 1;

    // XCD-chunked swizzle over the (x,y) plane (bijective when nxy%8==0)
    int bx = blockIdx.x, by = blockIdx.y;
    {
        int nxy = gridDim.x * gridDim.y;
        if ((nxy & 7) == 0) {
            int bid = by * gridDim.x + bx;
            int wgs = (bid & 7) * (nxy >> 3) + (bid >> 3);
            bx = wgs % gridDim.x;
            by = wgs / gridDim.x;
        }
    }
    const int m0 = by * 128, n0 = bx * BN;
    const long z = blockIdx.z;
    const float es = (z == 0 || !scaleZ0) ? scale : 1.f;
    A  += z * sA;
    BT += z * sBT;
    C  += z * sC;

    fx4 acc[TM][TN] = {};

    for (int k0 = 0; k0 < K; k0 += BK) {
        #pragma unroll
        for (int i = 0; i < AI; ++i) {
            unsigned base = (unsigned)(w * AI + i) * 1024u;
            unsigned off  = base + (unsigned)lane * 16u;
            unsigned row  = off >> 6;
            unsigned col  = (off & 63u) >> 1;
            GLDS(A + (long)(m0 + row) * ldA + k0 + col, (char*)As + base);
        }
        #pragma unroll
        for (int i = 0; i < BI; ++i) {
            unsigned base = (unsigned)(w * BI + i) * 1024u;
            unsigned off  = base + (unsigned)lane * 16u;
            unsigned row  = off >> 6;
            unsigned col  = (off & 63u) >> 1;
            GLDS(BT + (long)(n0 + row) * ldBT + k0 + col, (char*)Bs + base);
        }
        __syncthreads();

        sx8 af[TM], bfr[TN];
        #pragma unroll
        for (int r = 0; r < TM; ++r)
            af[r] = *(const sx8*)&As[(wrow * 64 + r * 16 + n16) * BK + quad * 8];
        #pragma unroll
        for (int c = 0; c < TN; ++c)
            bfr[c] = *(const sx8*)&Bs[(wcol * (TN * 16) + c * 16 + n16) * BK + quad * 8];
        #pragma unroll
        for (int r = 0; r < TM; ++r)
            #pragma unroll
            for (int c = 0; c < TN; ++c)
                acc[r][c] = MFMA(af[r], bfr[c], acc[r][c]);
        __syncthreads();
    }

    #pragma unroll
    for (int r = 0; r < TM; ++r) {
        int row = m0 + wrow * 64 + r * 16 + quad * 4;
        #pragma unroll
        for (int c = 0; c < TN; ++c) {
            int col = n0 + wcol * (TN * 16) + c * 16 + n16;
            float bv = bias ? bf2f(bias[bz * (int)z + col]) : 0.f;
            #pragma unroll
            for (int g = 0; g < 4; ++g) {
                long idx = (long)(row + g) * ldC + col;
                float xv = acc[r][c][g] * es + bv;
                if (resid)
                    xv += residF32 ? ((const float*)resid)[rofs + idx]
                                   : bf2f(((const u16*)resid)[rofs + idx]);
                if (relu) xv = fmaxf(xv, 0.f);
                C[idx] = f2bf(xv);
            }
        }
    }
}

// ---------- fused attention: S=(Q/8)@Kt, head-softmax, O=PV, 2-way m-split ----------
// R5 = R2's proven 4-wave structure (best measured: 298 us) + R3's proven
// XCD-chunked swizzle (FETCH 294->210 MB) + Q prescaled by 1/8 in QKV GEMM.
// Head-softmax is pointwise in (l,m) -> m splits across blocks; PV partial
// sums reduced by add_bf afterwards.
// 1D grid 1024; wg = (bid&7)*128 + bid>>3: XCD k gets wg[k*128,(k+1)*128) =
// all 64 l-tiles of 2 (b, m-half) groups -> its resident blocks share one
// 4MB K+V panel set = its L2.
// wg decode: l-tile = wg&63, b = (wg>>6)&7, m-half = wg>>9.
// qb [b][16h][1024 l][64 d]; kt [(b,h)][m][d] reshape-view K_t; vt [b][16h][64 d][1024 m].
// QK uses SWAPPED operands mfma(K,Q) so D = S^T[m][l] with 4 consecutive m per
// lane -> one packed ds_write_b64.
__global__ __launch_bounds__(256, 4) void attn_fused(
    const u16* __restrict__ qb, const u16* __restrict__ kt,
    const u16* __restrict__ vt, const int* __restrict__ mask,
    u16* __restrict__ p0, u16* __restrict__ p1)
{
    constexpr int MC = 64;           // m-chunk
    constexpr int LM = MC + 8;       // 72 (pad; rows stay 16B-aligned: 144B stride)
    constexpr int SH = 16 * LM;      // per-head stride = 1152 u16
    __shared__ __align__(16) u16 Ss[16 * SH];   // 36,864 B

    const int tid = threadIdx.x, w = tid >> 6, lane = tid & 63;
    const int quad = lane >> 4, n16 = lane & 15;

    // XCD-chunked swizzle (1024 blocks, 8 XCDs, bijective)
    const int wg = ((blockIdx.x & 7) << 7) + (blockIdx.x >> 3);
    const int l0 = (wg & 63) * 16;
    const long bo = (long)((wg >> 6) & 7) * 1048576;
    const int zz = wg >> 9;
    const int mbase = zz * 512;
    u16* __restrict__ po = zz ? p1 : p0;

    // resident Q B-frags for this wave's 4 heads (col=l, k=d); Q pre-scaled 1/8
    sx8 qf[4][2];
    #pragma unroll
    for (int i = 0; i < 4; ++i) {
        const u16* qp = qb + bo + (w * 4 + i) * 65536 + (l0 + n16) * 64 + quad * 8;
        qf[i][0] = *(const sx8*)qp;
        qf[i][1] = *(const sx8*)(qp + 32);
    }

    fx4 of[4][4] = {};   // partial-O accumulators [head][d-tile]

    for (int mt = 0; mt < 8; ++mt) {
        const int m0 = mbase + mt * MC;
        // ---- S^T = K @ (Q/8)^T : A-frag rows = m (from kt), B-frag cols = l ----
        #pragma unroll
        for (int i = 0; i < 4; ++i) {
            const int h = w * 4 + i;
            const u16* kp = kt + bo + h * 65536 + (long)m0 * 64;
            #pragma unroll
            for (int nt = 0; nt < 4; ++nt) {
                const u16* kr = kp + (nt * 16 + n16) * 64 + quad * 8;
                fx4 s = {};
                s = MFMA(*(const sx8*)kr,        qf[i][0], s);
                s = MFMA(*(const sx8*)(kr + 32), qf[i][1], s);
                // D: row = m = quad*4 + reg (consecutive), col = l = n16
                uint2 pk;
                pk.x = (unsigned)f2bf(s[0]) | ((unsigned)f2bf(s[1]) << 16);
                pk.y = (unsigned)f2bf(s[2]) | ((unsigned)f2bf(s[3]) << 16);
                *(uint2*)&Ss[h * SH + n16 * LM + nt * 16 + quad * 4] = pk;
            }
        }
        __syncthreads();
        // ---- softmax over the 16 heads, pointwise in (l,m) ----
        // pair-packed: 16 l x 32 m-pairs = 512 positions, 2 per thread.
        #pragma unroll
        for (int j = 0; j < 2; ++j) {
            const int p = tid + 256 * j;          // pair index 0..511
            const int l = p >> 5, mp = (p & 31) * 2;
            const int2 mk = *(const int2*)&mask[bo + (long)(l0 + l) * 1024 + m0 + mp];
            u16* col = &Ss[l * LM + mp];
            float v0[16], v1[16], mx0 = -1e30f, mx1 = -1e30f;
            #pragma unroll
            for (int h = 0; h < 16; ++h) {
                unsigned pr = *(const unsigned*)&col[h * SH];
                float a = (mk.x == 0) ? -1e-12f : bf2f((u16)(pr & 0xffff));
                float b = (mk.y == 0) ? -1e-12f : bf2f((u16)(pr >> 16));
                v0[h] = a; v1[h] = b;
                mx0 = fmaxf(mx0, a); mx1 = fmaxf(mx1, b);
            }
            float s0 = 0.f, s1 = 0.f;
            #pragma unroll
            for (int h = 0; h < 16; ++h) {
                v0[h] = __expf(v0[h] - mx0); s0 += v0[h];
                v1[h] = __expf(v1[h] - mx1); s1 += v1[h];
            }
            const float i0 = 1.f / s0, i1 = 1.f / s1;
            #pragma unroll
            for (int h = 0; h < 16; ++h)
                *(unsigned*)&col[h * SH] =
                    (unsigned)f2bf(v0[h] * i0) | ((unsigned)f2bf(v1[h] * i1) << 16);
        }
        __syncthreads();
        // ---- O += P @ V (A-frag rows = l from Ss, B-frag from vt, m contiguous) ----
        #pragma unroll
        for (int i = 0; i < 4; ++i) {
            const int h = w * 4 + i;
            const u16* sp = &Ss[h * SH + n16 * LM];
            sx8 a0 = *(const sx8*)(sp + quad * 8);
            sx8 a1 = *(const sx8*)(sp + 32 + quad * 8);
            const u16* vp = vt + bo + h * 65536 + (long)n16 * 1024 + m0 + quad * 8;
            #pragma unroll
            for (int dt = 0; dt < 4; ++dt) {
                of[i][dt] = MFMA(a0, *(const sx8*)(vp + dt * 16384),      of[i][dt]);
                of[i][dt] = MFMA(a1, *(const sx8*)(vp + dt * 16384 + 32), of[i][dt]);
            }
        }
        __syncthreads();
    }

    // ---- epilogue: head-major flat store of this half's partial O ----
    #pragma unroll
    for (int i = 0; i < 4; ++i) {
        const int h = w * 4 + i;
        #pragma unroll
        for (int dt = 0; dt < 4; ++dt)
            #pragma unroll
            for (int r = 0; r < 4; ++r)
                po[bo + h * 65536 + (long)(l0 + quad * 4 + r) * 64 + dt * 16 + n16]
                    = f2bf(of[i][dt][r]);
    }
}

// ---------- bf16 partial-O reduction: b := bf16(a + b), element-wise in-place ----------
__global__ __launch_bounds__(256) void add_bf(
    const u16* __restrict__ a, u16* __restrict__ b)
{
    long i = ((long)blockIdx.x * 256 + threadIdx.x) * 8;
    uint4 x = *(const uint4*)(a + i);
    uint4 y = *(const uint4*)(b + i);
    uint4 r;
    unsigned* xp = (unsigned*)&x; unsigned* yp = (unsigned*)&y; unsigned* rp = (unsigned*)&r;
    #pragma unroll
    for (int k = 0; k < 4; ++k) {
        float lo = bf2f((u16)(xp[k] & 0xffff)) + bf2f((u16)(yp[k] & 0xffff));
        float hi = bf2f((u16)(xp[k] >> 16))    + bf2f((u16)(yp[k] >> 16));
        rp[k] = (unsigned)f2bf(lo) | ((unsigned)f2bf(hi) << 16);
    }
    *(uint4*)(b + i) = r;
}

// ---------- fp32 -> bf16 elementwise ----------
__global__ __launch_bounds__(256) void convert_f2b(
    const float* __restrict__ in, u16* __restrict__ out)
{
    long i = ((long)blockIdx.x * 256 + threadIdx.x) * 4;
    fx4 v = *(const fx4*)(in + i);
    uint2 o;
    o.x = (unsigned)f2bf(v[0]) | ((unsigned)f2bf(v[1]) << 16);
    o.y = (unsigned)f2bf(v[2]) | ((unsigned)f2bf(v[3]) << 16);
    *(uint2*)(out + i) = o;
}

// ---------- fp32 [R][C] -> bf16 transposed [C][R] ----------
__global__ __launch_bounds__(256) void transpose_f2b(
    const float* __restrict__ in, u16* __restrict__ out, int R, int C)
{
    __shared__ float t[32][33];
    int c0 = blockIdx.x * 32, r0 = blockIdx.y * 32;
    int tx = threadIdx.x & 31, ty = threadIdx.x >> 5;
    #pragma unroll
    for (int i = 0; i < 4; ++i)
        t[ty + i * 8][tx] = in[(long)(r0 + ty + i * 8) * C + c0 + tx];
    __syncthreads();
    #pragma unroll
    for (int i = 0; i < 4; ++i)
        out[(long)(c0 + ty + i * 8) * R + r0 + tx] = f2bf(t[tx][ty + i * 8]);
}

// ---------- bf16 batched transpose ----------
__global__ __launch_bounds__(256) void transpose_bf(
    const u16* __restrict__ in, u16* __restrict__ out, int R, int C)
{
    __shared__ u16 t[32][33];
    long zoff = (long)blockIdx.z * (long)R * (long)C;
    in += zoff; out += zoff;
    int c0 = blockIdx.x * 32, r0 = blockIdx.y * 32;
    int tx = threadIdx.x & 31, ty = threadIdx.x >> 5;
    #pragma unroll
    for (int i = 0; i < 4; ++i)
        t[ty + i * 8][tx] = in[(long)(r0 + ty + i * 8) * C + c0 + tx];
    __syncthreads();
    #pragma unroll
    for (int i = 0; i < 4; ++i)
        out[(long)(c0 + ty + i * 8) * R + r0 + tx] = t[tx][ty + i * 8];
}

// ---------- pack biases fp32 -> bf16 [bq|bk|bv|bc|b1|b2]; bq pre-scaled 1/8 ----------
__global__ __launch_bounds__(256) void pack_bias(
    const float* bq, const float* bk, const float* bv, const float* bc,
    const float* b1, const float* b2, u16* __restrict__ out)
{
    int i = blockIdx.x * 256 + threadIdx.x;
    float v;
    if      (i < 1024) v = bq[i] * 0.125f;
    else if (i < 2048) v = bk[i - 1024];
    else if (i < 3072) v = bv[i - 2048];
    else if (i < 4096) v = bc[i - 3072];
    else if (i < 8192) v = b1[i - 4096];
    else               v = b2[i - 8192];
    out[i] = f2bf(v);
}

// ---------- LayerNorm (ddof=1, /(std+eps)) ----------
__global__ __launch_bounds__(256) void layernorm_row(
    const u16* __restrict__ in, const float* __restrict__ g,
    const float* __restrict__ be, void* __restrict__ out, int outF32)
{
    int wave = threadIdx.x >> 6, lane = threadIdx.x & 63;
    long row = (long)blockIdx.x * 4 + wave;
    const u16* p = in + row * 1024 + lane * 16;

    float x[16];
    uint4 a = ((const uint4*)p)[0], b = ((const uint4*)p)[1];
    {
        unsigned u;
        u = a.x; x[0] = bf2f(u & 0xffff);  x[1] = bf2f(u >> 16);
        u = a.y; x[2] = bf2f(u & 0xffff);  x[3] = bf2f(u >> 16);
        u = a.z; x[4] = bf2f(u & 0xffff);  x[5] = bf2f(u >> 16);
        u = a.w; x[6] = bf2f(u & 0xffff);  x[7] = bf2f(u >> 16);
        u = b.x; x[8] = bf2f(u & 0xffff);  x[9] = bf2f(u >> 16);
        u = b.y; x[10] = bf2f(u & 0xffff); x[11] = bf2f(u >> 16);
        u = b.z; x[12] = bf2f(u & 0xffff); x[13] = bf2f(u >> 16);
        u = b.w; x[14] = bf2f(u & 0xffff); x[15] = bf2f(u >> 16);
    }
    float s = 0.f, ss = 0.f;
    #pragma unroll
    for (int i = 0; i < 16; ++i) { s += x[i]; ss += x[i] * x[i]; }
    #pragma unroll
    for (int o = 32; o >= 1; o >>= 1) { s += __shfl_down(s, o); ss += __shfl_down(ss, o); }
    s = __shfl(s, 0); ss = __shfl(ss, 0);
    float mean = s * (1.f / 1024.f);
    float var  = fmaxf((ss - 1024.f * mean * mean) * (1.f / 1023.f), 0.f);
    float rinv = 1.f / (sqrtf(var) + 1e-12f);

    int col = lane * 16;
    if (outF32) {
        float* ov = (float*)out + row * 1024 + col;
        #pragma unroll
        for (int i = 0; i < 16; ++i)
            ov[i] = g[col + i] * ((x[i] - mean) * rinv) + be[col + i];
    } else {
        u16* ov = (u16*)out + row * 1024 + col;
        #pragma unroll
        for (int i = 0; i < 16; ++i)
            ov[i] = f2bf(g[col + i] * ((x[i] - mean) * rinv) + be[col + i]);
    }
}

// ---------- launch ----------
// ws map (MB; peak 96 + 18KB bias):
//  [0,16)  xb -> p0 (m-half-0 partial O)
//  [16,22) wqkvT  [22,24) wcT
//  [24,40) qb -> t0/x1
//  [40,56) kb -> vt (full V^T over dead kb) -> fh lower
//  [56,72) vb -> p1 (m-half-1 partial O) -> ao (after add_bf) -> fh upper
//  [72,88) kt (reshape-view K_t, all b) -> w1T/w2T post-attention
//  [88,96) pre2 (FFN phase; free during attention)
//  [96,+18KB) packed biases
extern "C" void kernel_launch(void* const* d_in, const int* in_sizes, int n_in,
                              void* d_out, int out_size, void* d_ws, size_t ws_size,
                              hipStream_t stream)
{
    const float* xf  = (const float*)d_in[0];
    const int* mask  = (const int*)d_in[1];
    const float* wq = (const float*)d_in[2];  const float* bq = (const float*)d_in[3];
    const float* wk = (const float*)d_in[4];  const float* bk = (const float*)d_in[5];
    const float* wv = (const float*)d_in[6];  const float* bv = (const float*)d_in[7];
    const float* wc = (const float*)d_in[8];  const float* bc = (const float*)d_in[9];
    const float* g1 = (const float*)d_in[10]; const float* be1 = (const float*)d_in[11];
    const float* w1 = (const float*)d_in[12]; const float* b1 = (const float*)d_in[13];
    const float* w2 = (const float*)d_in[14]; const float* b2 = (const float*)d_in[15];
    const float* g2 = (const float*)d_in[16]; const float* be2 = (const float*)d_in[17];

    char* ws = (char*)d_ws;
    const long MB = 1 << 20;
    u16* xb    = (u16*)(ws + 0 * MB);
    u16* wqkvT = (u16*)(ws + 16 * MB);
    u16* wcT   = (u16*)(ws + 22 * MB);
    u16* qb    = (u16*)(ws + 24 * MB);
    u16* kb    = (u16*)(ws + 40 * MB);
    u16* vb    = (u16*)(ws + 56 * MB);
    u16* kt    = (u16*)(ws + 72 * MB);
    u16* vt    = (u16*)(ws + 40 * MB);     // full V^T overlays dead kb
    u16* biasp = (u16*)(ws + 96 * MB);
    u16* p0   = xb;                        // m-half-0 partial O
    u16* p1   = vb;                        // m-half-1 partial O; becomes ao
    u16* ao   = p1;
    u16* t0   = qb;
    u16* fh   = kb;
    u16* w1T  = (u16*)(ws + 72 * MB);      // overlay kt post-attention
    u16* w2T  = (u16*)(ws + 80 * MB);
    u16* pre2 = (u16*)(ws + 88 * MB);

    dim3 blk(256);
    const long M1 = 1048576;

    // phase 0: conversions
    convert_f2b<<<dim3(8192), blk, 0, stream>>>(xf, xb);
    transpose_f2b<<<dim3(32, 32), blk, 0, stream>>>(wq, wqkvT, 1024, 1024);
    transpose_f2b<<<dim3(32, 32), blk, 0, stream>>>(wk, wqkvT + M1, 1024, 1024);
    transpose_f2b<<<dim3(32, 32), blk, 0, stream>>>(wv, wqkvT + 2 * M1, 1024, 1024);
    transpose_f2b<<<dim3(32, 32), blk, 0, stream>>>(wc, wcT, 1024, 1024);
    pack_bias<<<dim3(36), blk, 0, stream>>>(bq, bk, bv, bc, b1, b2, biasp);

    // phase 1: fused QKV (Q projection pre-scaled by 1/8: scale=0.125, z==0 only)
    gemm_bt<128><<<dim3(8, 64, 3), blk, 0, stream>>>(
        xb, 0, 1024, wqkvT, M1, 1024, qb, 8 * M1, 1024, 1024,
        biasp, 1024, nullptr, 0, 0, 0.125f, 1, 0);

    // phase 2: kt = reshape-view K_t transposed to [m][d], all (b,h)
    //          (must precede vt, which overwrites kb)
    transpose_bf<<<dim3(32, 2, 128), blk, 0, stream>>>(kb, kt, 64, 1024);

    // phase 3: full V^T, then 1024-block fused attention (XCD-swizzled, 4-wave)
    transpose_bf<<<dim3(2, 32, 128), blk, 0, stream>>>(vb, vt, 1024, 64);
    attn_fused<<<dim3(1024), blk, 0, stream>>>(qb, kt, vt, mask, p0, p1);
    // partial-O reduction: ao := p0 + p1 (in-place into p1)
    add_bf<<<dim3(4096), blk, 0, stream>>>(p0, p1);

    // phase 4: out-proj + bias + resid(x) -> t0 ; LN1 in-place
    gemm_bt<128><<<dim3(8, 64, 1), blk, 0, stream>>>(
        ao, 0, 1024, wcT, 0, 1024, t0, 0, 1024, 1024,
        biasp + 3072, 0, xf, 1, 0, 1.f, 0, 0);
    layernorm_row<<<dim3(2048), blk, 0, stream>>>(t0, g1, be1, t0, 0);

    // phase 5: FFN weight transposes into dead kt region
    transpose_f2b<<<dim3(128, 32), blk, 0, stream>>>(w1, w1T, 1024, 4096);
    transpose_f2b<<<dim3(32, 128), blk, 0, stream>>>(w2, w2T, 4096, 1024);

    // phase 6: FFN + LN2, 2 chunks of 4096 rows
    for (int c = 0; c < 2; ++c) {
        long r0 = (long)c * 4096 * 1024;
        gemm_bt<128><<<dim3(32, 32, 1), blk, 0, stream>>>(
            t0 + r0, 0, 1024, w1T, 0, 1024, fh, 0, 4096, 1024,
            biasp + 4096, 0, nullptr, 0, 0, 1.f, 0, 1);
        gemm_bt<64><<<dim3(16, 32, 1), blk, 0, stream>>>(
            fh, 0, 4096, w2T, 0, 4096, pre2, 0, 1024, 4096,
            biasp + 8192, 0, t0 + r0, 0, 0, 1.f, 0, 0);
        layernorm_row<<<dim3(1024), blk, 0, stream>>>(
            pre2, g2, be2, (float*)d_out + r0, 1);
    }
}

// Round 8
// 925.375 us; speedup vs baseline: 1.3282x; 1.0096x over previous
//
#include <hip/hip_runtime.h>
#include <stdint.h>

typedef unsigned short u16;
typedef __attribute__((ext_vector_type(8))) short sx8;   // 8 bf16 (4 VGPRs) — MFMA A/B frag
typedef __attribute__((ext_vector_type(4))) float fx4;   // MFMA C/D frag

__device__ __forceinline__ float bf2f(u16 u) {
    union { unsigned i; float f; } v; v.i = ((unsigned)u) << 16; return v.f;
}
__device__ __forceinline__ u16 f2bf(float f) {
    union { float f; unsigned i; } v; v.f = f;
    return (u16)((v.i + 0x7FFFu + ((v.i >> 16) & 1u)) >> 16);
}
#define MFMA(a, b, c) __builtin_amdgcn_mfma_f32_16x16x32_bf16((a), (b), (c), 0, 0, 0)

#define GLDS(gp, lp) \
    __builtin_amdgcn_global_load_lds((const __attribute__((address_space(1))) void*)(gp), \
                                     (__attribute__((address_space(3))) void*)(lp), 16, 0, 0)

// 0.125 (1/sqrt(64)) * log2(e): attention scale folded with the exp->exp2
// domain change. Softmax keeps max-subtraction (sum >= 1, NaN-proof);
// 2^(S'-mx)/sum equals natural-exp softmax exactly (base change cancels).
#define QSCALE 0.18033688011112042f
// masked score -1e-12 nats -> log2 domain
#define MASKC (-1.442695e-12f)

// ---------- m97-style MFMA GEMM: C[M,N] = A[M,K] @ BT[N,K]^T, all bf16 ----------
// scaleZ0: when set, `scale` applies only to batch z==0 (folds the attention
// scale into the Q projection of the fused QKV GEMM).
template<int BN>
__global__ __launch_bounds__(256) void gemm_bt(
    const u16* __restrict__ A, long sA, int ldA,
    const u16* __restrict__ BT, long sBT, int ldBT,
    u16* __restrict__ C, long sC, int ldC,
    int K,
    const u16* __restrict__ bias, int bz,
    const void* __restrict__ resid, int residF32, long rofs,
    float scale, int scaleZ0, int relu)
{
    constexpr int BK = 32;
    constexpr int TM = 4;
    constexpr int TN = BN / 32;
    constexpr int AI = 2;
    constexpr int BI = BN / 64;

    __shared__ __align__(16) u16 As[128 * BK];
    __shared__ __align__(16) u16 Bs[BN * BK];

    const int tid  = threadIdx.x;
    const int w    = tid >> 6;
    const int lane = tid & 63;
    const int quad = lane >> 4;
    const int n16  = lane & 15;
    const int wrow = w >> 1, wcol = w & 1;

    // XCD-chunked swizzle over the (x,y) plane (bijective when nxy%8==0)
    int bx = blockIdx.x, by = blockIdx.y;
    {
        int nxy = gridDim.x * gridDim.y;
        if ((nxy & 7) == 0) {
            int bid = by * gridDim.x + bx;
            int wgs = (bid & 7) * (nxy >> 3) + (bid >> 3);
            bx = wgs % gridDim.x;
            by = wgs / gridDim.x;
        }
    }
    const int m0 = by * 128, n0 = bx * BN;
    const long z = blockIdx.z;
    const float es = (z == 0 || !scaleZ0) ? scale : 1.f;
    A  += z * sA;
    BT += z * sBT;
    C  += z * sC;

    fx4 acc[TM][TN] = {};

    for (int k0 = 0; k0 < K; k0 += BK) {
        #pragma unroll
        for (int i = 0; i < AI; ++i) {
            unsigned base = (unsigned)(w * AI + i) * 1024u;
            unsigned off  = base + (unsigned)lane * 16u;
            unsigned row  = off >> 6;
            unsigned col  = (off & 63u) >> 1;
            GLDS(A + (long)(m0 + row) * ldA + k0 + col, (char*)As + base);
        }
        #pragma unroll
        for (int i = 0; i < BI; ++i) {
            unsigned base = (unsigned)(w * BI + i) * 1024u;
            unsigned off  = base + (unsigned)lane * 16u;
            unsigned row  = off >> 6;
            unsigned col  = (off & 63u) >> 1;
            GLDS(BT + (long)(n0 + row) * ldBT + k0 + col, (char*)Bs + base);
        }
        __syncthreads();

        sx8 af[TM], bfr[TN];
        #pragma unroll
        for (int r = 0; r < TM; ++r)
            af[r] = *(const sx8*)&As[(wrow * 64 + r * 16 + n16) * BK + quad * 8];
        #pragma unroll
        for (int c = 0; c < TN; ++c)
            bfr[c] = *(const sx8*)&Bs[(wcol * (TN * 16) + c * 16 + n16) * BK + quad * 8];
        #pragma unroll
        for (int r = 0; r < TM; ++r)
            #pragma unroll
            for (int c = 0; c < TN; ++c)
                acc[r][c] = MFMA(af[r], bfr[c], acc[r][c]);
        __syncthreads();
    }

    #pragma unroll
    for (int r = 0; r < TM; ++r) {
        int row = m0 + wrow * 64 + r * 16 + quad * 4;
        #pragma unroll
        for (int c = 0; c < TN; ++c) {
            int col = n0 + wcol * (TN * 16) + c * 16 + n16;
            float bv = bias ? bf2f(bias[bz * (int)z + col]) : 0.f;
            #pragma unroll
            for (int g = 0; g < 4; ++g) {
                long idx = (long)(row + g) * ldC + col;
                float xv = acc[r][c][g] * es + bv;
                if (resid)
                    xv += residF32 ? ((const float*)resid)[rofs + idx]
                                   : bf2f(((const u16*)resid)[rofs + idx]);
                if (relu) xv = fmaxf(xv, 0.f);
                C[idx] = f2bf(xv);
            }
        }
    }
}

// ---------- fused attention: S'=(Q*QSCALE)@Kt, head-softmax (exp2+max), O=PV ----------
// R8 bisect of the R6/R7 NaN: suspected cause was v_cvt_pk inline asm reading
// RAW MFMA results (unhandled MFMA->asm-VALU hazard; the recognizer can't see
// into asm text). So:
//  * S-store: f2bf IR path (R5-proven; compiler handles the MFMA hazard).
//  * P-store: cvt_pk asm on plain-VALU inputs (exact R4-proven pattern).
//  * exp2-domain WITH max-sub (sum>=1, NaN-proof); rcpf builtin for 1/sum.
//  * mask prefetched at iter start (plain loads; hides L2 latency under QK).
// Head-softmax is pointwise in (l,m) -> m split across blocks (2 halves),
// partial O reduced by add_bf. XCD-chunked swizzle (R3-proven).
// qb [b][16h][1024 l][64 d]; kt [(b,h)][m][d] reshape-view K_t; vt [b][16h][64 d][1024 m].
__global__ __launch_bounds__(256, 4) void attn_fused(
    const u16* __restrict__ qb, const u16* __restrict__ kt,
    const u16* __restrict__ vt, const int* __restrict__ mask,
    u16* __restrict__ p0, u16* __restrict__ p1)
{
    constexpr int MC = 64;           // m-chunk
    constexpr int LM = MC + 8;       // 72 (pad; rows stay 16B-aligned: 144B stride)
    constexpr int SH = 16 * LM;      // per-head stride = 1152 u16
    __shared__ __align__(16) u16 Ss[16 * SH];   // 36,864 B

    const int tid = threadIdx.x, w = tid >> 6, lane = tid & 63;
    const int quad = lane >> 4, n16 = lane & 15;

    // XCD-chunked swizzle (1024 blocks, 8 XCDs, bijective)
    const int wg = ((blockIdx.x & 7) << 7) + (blockIdx.x >> 3);
    const int l0 = (wg & 63) * 16;
    const long bo = (long)((wg >> 6) & 7) * 1048576;
    const int zz = wg >> 9;
    const int mbase = zz * 512;
    u16* __restrict__ po = zz ? p1 : p0;

    // softmax work split: thread covers (l, m-pair) p = tid + 256*j
    const int sl0 = tid >> 5,         smp0 = (tid & 31) * 2;
    const int sl1 = (tid + 256) >> 5, smp1 = ((tid + 256) & 31) * 2;

    // resident Q B-frags for this wave's 4 heads (col=l, k=d); Q pre-scaled
    sx8 qf[4][2];
    #pragma unroll
    for (int i = 0; i < 4; ++i) {
        const u16* qp = qb + bo + (w * 4 + i) * 65536 + (l0 + n16) * 64 + quad * 8;
        qf[i][0] = *(const sx8*)qp;
        qf[i][1] = *(const sx8*)(qp + 32);
    }

    fx4 of[4][4] = {};   // partial-O accumulators [head][d-tile]

    for (int mt = 0; mt < 8; ++mt) {
        const int m0 = mbase + mt * MC;
        // ---- mask prefetch (plain loads; complete by the QK->softmax barrier) ----
        const int2 mk0 = *(const int2*)&mask[bo + (long)(l0 + sl0) * 1024 + m0 + smp0];
        const int2 mk1 = *(const int2*)&mask[bo + (long)(l0 + sl1) * 1024 + m0 + smp1];
        // ---- S'^T = K @ Qs^T : A-frag rows = m (from kt), B-frag cols = l ----
        #pragma unroll
        for (int i = 0; i < 4; ++i) {
            const int h = w * 4 + i;
            const u16* kp = kt + bo + h * 65536 + (long)m0 * 64;
            #pragma unroll
            for (int nt = 0; nt < 4; ++nt) {
                const u16* kr = kp + (nt * 16 + n16) * 64 + quad * 8;
                fx4 s = {};
                s = MFMA(*(const sx8*)kr,        qf[i][0], s);
                s = MFMA(*(const sx8*)(kr + 32), qf[i][1], s);
                // D: row = m = quad*4 + reg (consecutive), col = l = n16
                // f2bf IR path (NOT asm): compiler inserts the MFMA->VALU hazard waits
                uint2 pk;
                pk.x = (unsigned)f2bf(s[0]) | ((unsigned)f2bf(s[1]) << 16);
                pk.y = (unsigned)f2bf(s[2]) | ((unsigned)f2bf(s[3]) << 16);
                *(uint2*)&Ss[h * SH + n16 * LM + nt * 16 + quad * 4] = pk;
            }
        }
        __syncthreads();
        // ---- softmax over 16 heads, pointwise in (l,m); exp2 domain + max-sub ----
        // pair-packed: 16 l x 32 m-pairs = 512 positions, 2 per thread.
        #pragma unroll
        for (int j = 0; j < 2; ++j) {
            const int l = j ? sl1 : sl0, mp = j ? smp1 : smp0;
            const int2 mk = j ? mk1 : mk0;
            u16* col = &Ss[l * LM + mp];
            float v0[16], v1[16], mx0 = -1e30f, mx1 = -1e30f;
            #pragma unroll
            for (int h = 0; h < 16; ++h) {
                unsigned pr = *(const unsigned*)&col[h * SH];
                float a = (mk.x == 0) ? MASKC : bf2f((u16)(pr & 0xffff));
                float b = (mk.y == 0) ? MASKC : bf2f((u16)(pr >> 16));
                v0[h] = a; v1[h] = b;
                mx0 = fmaxf(mx0, a); mx1 = fmaxf(mx1, b);
            }
            float s0 = 0.f, s1 = 0.f;
            #pragma unroll
            for (int h = 0; h < 16; ++h) {
                v0[h] = exp2f(v0[h] - mx0); s0 += v0[h];
                v1[h] = exp2f(v1[h] - mx1); s1 += v1[h];
            }
            const float i0 = __builtin_amdgcn_rcpf(s0);
            const float i1 = __builtin_amdgcn_rcpf(s1);
            #pragma unroll
            for (int h = 0; h < 16; ++h) {
                // cvt_pk on plain VALU inputs — the exact R4-proven pattern
                float e0 = v0[h] * i0, e1 = v1[h] * i1;
                unsigned pk_;
                asm("v_cvt_pk_bf16_f32 %0, %1, %2" : "=v"(pk_) : "v"(e0), "v"(e1));
                *(unsigned*)&col[h * SH] = pk_;
            }
        }
        __syncthreads();
        // ---- O += P @ V (A-frag rows = l from Ss, B-frag from vt, m contiguous) ----
        #pragma unroll
        for (int i = 0; i < 4; ++i) {
            const int h = w * 4 + i;
            const u16* sp = &Ss[h * SH + n16 * LM];
            sx8 a0 = *(const sx8*)(sp + quad * 8);
            sx8 a1 = *(const sx8*)(sp + 32 + quad * 8);
            const u16* vp = vt + bo + h * 65536 + (long)n16 * 1024 + m0 + quad * 8;
            #pragma unroll
            for (int dt = 0; dt < 4; ++dt) {
                of[i][dt] = MFMA(a0, *(const sx8*)(vp + dt * 16384),      of[i][dt]);
                of[i][dt] = MFMA(a1, *(const sx8*)(vp + dt * 16384 + 32), of[i][dt]);
            }
        }
        __syncthreads();
    }

    // ---- epilogue: head-major flat store of this half's partial O ----
    #pragma unroll
    for (int i = 0; i < 4; ++i) {
        const int h = w * 4 + i;
        #pragma unroll
        for (int dt = 0; dt < 4; ++dt)
            #pragma unroll
            for (int r = 0; r < 4; ++r)
                po[bo + h * 65536 + (long)(l0 + quad * 4 + r) * 64 + dt * 16 + n16]
                    = f2bf(of[i][dt][r]);
    }
}

// ---------- bf16 partial-O reduction: b := bf16(a + b), element-wise in-place ----------
__global__ __launch_bounds__(256) void add_bf(
    const u16* __restrict__ a, u16* __restrict__ b)
{
    long i = ((long)blockIdx.x * 256 + threadIdx.x) * 8;
    uint4 x = *(const uint4*)(a + i);
    uint4 y = *(const uint4*)(b + i);
    uint4 r;
    unsigned* xp = (unsigned*)&x; unsigned* yp = (unsigned*)&y; unsigned* rp = (unsigned*)&r;
    #pragma unroll
    for (int k = 0; k < 4; ++k) {
        float lo = bf2f((u16)(xp[k] & 0xffff)) + bf2f((u16)(yp[k] & 0xffff));
        float hi = bf2f((u16)(xp[k] >> 16))    + bf2f((u16)(yp[k] >> 16));
        rp[k] = (unsigned)f2bf(lo) | ((unsigned)f2bf(hi) << 16);
    }
    *(uint4*)(b + i) = r;
}

// ---------- fp32 -> bf16 elementwise ----------
__global__ __launch_bounds__(256) void convert_f2b(
    const float* __restrict__ in, u16* __restrict__ out)
{
    long i = ((long)blockIdx.x * 256 + threadIdx.x) * 4;
    fx4 v = *(const fx4*)(in + i);
    uint2 o;
    o.x = (unsigned)f2bf(v[0]) | ((unsigned)f2bf(v[1]) << 16);
    o.y = (unsigned)f2bf(v[2]) | ((unsigned)f2bf(v[3]) << 16);
    *(uint2*)(out + i) = o;
}

// ---------- 4x fp32 [1024][1024] -> bf16 transposed, one launch (z selects src) ----------
__global__ __launch_bounds__(256) void transpose4_f2b(
    const float* a0, const float* a1, const float* a2, const float* a3,
    u16* __restrict__ out)
{
    __shared__ float t[32][33];
    const float* in = blockIdx.z == 0 ? a0 : blockIdx.z == 1 ? a1
                    : blockIdx.z == 2 ? a2 : a3;
    out += (long)blockIdx.z * 1048576;
    int c0 = blockIdx.x * 32, r0 = blockIdx.y * 32;
    int tx = threadIdx.x & 31, ty = threadIdx.x >> 5;
    #pragma unroll
    for (int i = 0; i < 4; ++i)
        t[ty + i * 8][tx] = in[(long)(r0 + ty + i * 8) * 1024 + c0 + tx];
    __syncthreads();
    #pragma unroll
    for (int i = 0; i < 4; ++i)
        out[(long)(c0 + ty + i * 8) * 1024 + r0 + tx] = f2bf(t[tx][ty + i * 8]);
}

// ---------- fp32 [R][C] -> bf16 transposed [C][R] ----------
__global__ __launch_bounds__(256) void transpose_f2b(
    const float* __restrict__ in, u16* __restrict__ out, int R, int C)
{
    __shared__ float t[32][33];
    int c0 = blockIdx.x * 32, r0 = blockIdx.y * 32;
    int tx = threadIdx.x & 31, ty = threadIdx.x >> 5;
    #pragma unroll
    for (int i = 0; i < 4; ++i)
        t[ty + i * 8][tx] = in[(long)(r0 + ty + i * 8) * C + c0 + tx];
    __syncthreads();
    #pragma unroll
    for (int i = 0; i < 4; ++i)
        out[(long)(c0 + ty + i * 8) * R + r0 + tx] = f2bf(t[tx][ty + i * 8]);
}

// ---------- bf16 batched transpose ----------
__global__ __launch_bounds__(256) void transpose_bf(
    const u16* __restrict__ in, u16* __restrict__ out, int R, int C)
{
    __shared__ u16 t[32][33];
    long zoff = (long)blockIdx.z * (long)R * (long)C;
    in += zoff; out += zoff;
    int c0 = blockIdx.x * 32, r0 = blockIdx.y * 32;
    int tx = threadIdx.x & 31, ty = threadIdx.x >> 5;
    #pragma unroll
    for (int i = 0; i < 4; ++i)
        t[ty + i * 8][tx] = in[(long)(r0 + ty + i * 8) * C + c0 + tx];
    __syncthreads();
    #pragma unroll
    for (int i = 0; i < 4; ++i)
        out[(long)(c0 + ty + i * 8) * R + r0 + tx] = t[tx][ty + i * 8];
}

// ---------- pack biases fp32 -> bf16 [bq|bk|bv|bc|b1|b2]; bq pre-scaled QSCALE ----------
__global__ __launch_bounds__(256) void pack_bias(
    const float* bq, const float* bk, const float* bv, const float* bc,
    const float* b1, const float* b2, u16* __restrict__ out)
{
    int i = blockIdx.x * 256 + threadIdx.x;
    float v;
    if      (i < 1024) v = bq[i] * QSCALE;
    else if (i < 2048) v = bk[i - 1024];
    else if (i < 3072) v = bv[i - 2048];
    else if (i < 4096) v = bc[i - 3072];
    else if (i < 8192) v = b1[i - 4096];
    else               v = b2[i - 8192];
    out[i] = f2bf(v);
}

// ---------- LayerNorm (ddof=1, /(std+eps)) ----------
__global__ __launch_bounds__(256) void layernorm_row(
    const u16* __restrict__ in, const float* __restrict__ g,
    const float* __restrict__ be, void* __restrict__ out, int outF32)
{
    int wave = threadIdx.x >> 6, lane = threadIdx.x & 63;
    long row = (long)blockIdx.x * 4 + wave;
    const u16* p = in + row * 1024 + lane * 16;

    float x[16];
    uint4 a = ((const uint4*)p)[0], b = ((const uint4*)p)[1];
    {
        unsigned u;
        u = a.x; x[0] = bf2f(u & 0xffff);  x[1] = bf2f(u >> 16);
        u = a.y; x[2] = bf2f(u & 0xffff);  x[3] = bf2f(u >> 16);
        u = a.z; x[4] = bf2f(u & 0xffff);  x[5] = bf2f(u >> 16);
        u = a.w; x[6] = bf2f(u & 0xffff);  x[7] = bf2f(u >> 16);
        u = b.x; x[8] = bf2f(u & 0xffff);  x[9] = bf2f(u >> 16);
        u = b.y; x[10] = bf2f(u & 0xffff); x[11] = bf2f(u >> 16);
        u = b.z; x[12] = bf2f(u & 0xffff); x[13] = bf2f(u >> 16);
        u = b.w; x[14] = bf2f(u & 0xffff); x[15] = bf2f(u >> 16);
    }
    float s = 0.f, ss = 0.f;
    #pragma unroll
    for (int i = 0; i < 16; ++i) { s += x[i]; ss += x[i] * x[i]; }
    #pragma unroll
    for (int o = 32; o >= 1; o >>= 1) { s += __shfl_down(s, o); ss += __shfl_down(ss, o); }
    s = __shfl(s, 0); ss = __shfl(ss, 0);
    float mean = s * (1.f / 1024.f);
    float var  = fmaxf((ss - 1024.f * mean * mean) * (1.f / 1023.f), 0.f);
    float rinv = 1.f / (sqrtf(var) + 1e-12f);

    int col = lane * 16;
    if (outF32) {
        float* ov = (float*)out + row * 1024 + col;
        #pragma unroll
        for (int i = 0; i < 16; ++i)
            ov[i] = g[col + i] * ((x[i] - mean) * rinv) + be[col + i];
    } else {
        u16* ov = (u16*)out + row * 1024 + col;
        #pragma unroll
        for (int i = 0; i < 16; ++i)
            ov[i] = f2bf(g[col + i] * ((x[i] - mean) * rinv) + be[col + i]);
    }
}

// ---------- launch ----------
// ws map (MB; peak 96 + 18KB bias):
//  [0,16)  xb -> p0 (m-half-0 partial O)
//  [16,22) wqkvT  [22,24) wcT (contiguous: one transpose4 launch)
//  [24,40) qb -> t0/x1
//  [40,56) kb -> vt (full V^T over dead kb) -> fh lower
//  [56,72) vb -> p1 (m-half-1 partial O) -> ao (after add_bf) -> fh upper
//  [72,88) kt (reshape-view K_t, all b) -> w1T/w2T post-attention
//  [88,96) pre2 (FFN phase; free during attention)
//  [96,+18KB) packed biases
extern "C" void kernel_launch(void* const* d_in, const int* in_sizes, int n_in,
                              void* d_out, int out_size, void* d_ws, size_t ws_size,
                              hipStream_t stream)
{
    const float* xf  = (const float*)d_in[0];
    const int* mask  = (const int*)d_in[1];
    const float* wq = (const float*)d_in[2];  const float* bq = (const float*)d_in[3];
    const float* wk = (const float*)d_in[4];  const float* bk = (const float*)d_in[5];
    const float* wv = (const float*)d_in[6];  const float* bv = (const float*)d_in[7];
    const float* wc = (const float*)d_in[8];  const float* bc = (const float*)d_in[9];
    const float* g1 = (const float*)d_in[10]; const float* be1 = (const float*)d_in[11];
    const float* w1 = (const float*)d_in[12]; const float* b1 = (const float*)d_in[13];
    const float* w2 = (const float*)d_in[14]; const float* b2 = (const float*)d_in[15];
    const float* g2 = (const float*)d_in[16]; const float* be2 = (const float*)d_in[17];

    char* ws = (char*)d_ws;
    const long MB = 1 << 20;
    u16* xb    = (u16*)(ws + 0 * MB);
    u16* wqkvT = (u16*)(ws + 16 * MB);
    u16* wcT   = (u16*)(ws + 22 * MB);
    u16* qb    = (u16*)(ws + 24 * MB);
    u16* kb    = (u16*)(ws + 40 * MB);
    u16* vb    = (u16*)(ws + 56 * MB);
    u16* kt    = (u16*)(ws + 72 * MB);
    u16* vt    = (u16*)(ws + 40 * MB);     // full V^T overlays dead kb
    u16* biasp = (u16*)(ws + 96 * MB);
    u16* p0   = xb;                        // m-half-0 partial O
    u16* p1   = vb;                        // m-half-1 partial O; becomes ao
    u16* ao   = p1;
    u16* t0   = qb;
    u16* fh   = kb;
    u16* w1T  = (u16*)(ws + 72 * MB);      // overlay kt post-attention
    u16* w2T  = (u16*)(ws + 80 * MB);
    u16* pre2 = (u16*)(ws + 88 * MB);

    dim3 blk(256);
    const long M1 = 1048576;

    // phase 0: conversions (wq|wk|wv|wc in ONE launch; dst contiguous)
    convert_f2b<<<dim3(8192), blk, 0, stream>>>(xf, xb);
    transpose4_f2b<<<dim3(32, 32, 4), blk, 0, stream>>>(wq, wk, wv, wc, wqkvT);
    pack_bias<<<dim3(36), blk, 0, stream>>>(bq, bk, bv, bc, b1, b2, biasp);

    // phase 1: fused QKV (Q projection pre-scaled by 0.125*log2e: z==0 only)
    gemm_bt<128><<<dim3(8, 64, 3), blk, 0, stream>>>(
        xb, 0, 1024, wqkvT, M1, 1024, qb, 8 * M1, 1024, 1024,
        biasp, 1024, nullptr, 0, 0, QSCALE, 1, 0);

    // phase 2: kt = reshape-view K_t transposed to [m][d], all (b,h)
    //          (must precede vt, which overwrites kb)
    transpose_bf<<<dim3(32, 2, 128), blk, 0, stream>>>(kb, kt, 64, 1024);

    // phase 3: full V^T, then 1024-block fused attention (XCD-swizzled, 4-wave)
    transpose_bf<<<dim3(2, 32, 128), blk, 0, stream>>>(vb, vt, 1024, 64);
    attn_fused<<<dim3(1024), blk, 0, stream>>>(qb, kt, vt, mask, p0, p1);
    // partial-O reduction: ao := p0 + p1 (in-place into p1)
    add_bf<<<dim3(4096), blk, 0, stream>>>(p0, p1);

    // phase 4: out-proj + bias + resid(x) -> t0 ; LN1 in-place
    gemm_bt<128><<<dim3(8, 64, 1), blk, 0, stream>>>(
        ao, 0, 1024, wcT, 0, 1024, t0, 0, 1024, 1024,
        biasp + 3072, 0, xf, 1, 0, 1.f, 0, 0);
    layernorm_row<<<dim3(2048), blk, 0, stream>>>(t0, g1, be1, t0, 0);

    // phase 5: FFN weight transposes into dead kt region
    transpose_f2b<<<dim3(128, 32), blk, 0, stream>>>(w1, w1T, 1024, 4096);
    transpose_f2b<<<dim3(32, 128), blk, 0, stream>>>(w2, w2T, 4096, 1024);

    // phase 6: FFN + LN2, 2 chunks of 4096 rows
    for (int c = 0; c < 2; ++c) {
        long r0 = (long)c * 4096 * 1024;
        gemm_bt<128><<<dim3(32, 32, 1), blk, 0, stream>>>(
            t0 + r0, 0, 1024, w1T, 0, 1024, fh, 0, 4096, 1024,
            biasp + 4096, 0, nullptr, 0, 0, 1.f, 0, 1);
        gemm_bt<64><<<dim3(16, 32, 1), blk, 0, stream>>>(
            fh, 0, 4096, w2T, 0, 4096, pre2, 0, 1024, 4096,
            biasp + 8192, 0, t0 + r0, 0, 0, 1.f, 0, 0);
        layernorm_row<<<dim3(1024), blk, 0, stream>>>(
            pre2, g2, be2, (float*)d_out + r0, 1);
    }
}